// Round 11
// baseline (758.113 us; speedup 1.0000x reference)
//
#include <hip/hip_runtime.h>
#include <hip/hip_bf16.h>
#include <stdint.h>

typedef __bf16 bf16_t;
typedef __bf16 bf16x4 __attribute__((ext_vector_type(4)));
typedef __bf16 bf16x8 __attribute__((ext_vector_type(8)));
typedef float  f32x4  __attribute__((ext_vector_type(4)));

#define SCALE 0.17677669529663687f   // (192/6)^-0.5

__device__ __forceinline__ bf16_t tobf(float f) { return (bf16_t)f; }
__device__ __forceinline__ unsigned short bfbits(bf16_t v) {
  union { bf16_t f; unsigned short s; } u; u.f = v; return u.s;
}

__global__ void cvt_weights(const float* __restrict__ qkv_w,
                            const float* __restrict__ proj_w,
                            bf16_t* __restrict__ qkv_wb,
                            bf16_t* __restrict__ proj_wb)
{
  int i = blockIdx.x * 256 + threadIdx.x;
  if (i < 576 * 192) qkv_wb[i] = tobf(qkv_w[i]);
  if (i < 192 * 192) proj_wb[i] = tobf(proj_w[i]);
}

// GEMM1 tile body (half-pass form): xb0/xb1 are x fragments for token rows
// half*32+li / half*32+16+li, loaded ONCE per half and reused across tiles.
#define G1_TILE(NTV, WF)                                                        \
    {                                                                           \
      const int nt_  = (NTV);                                                   \
      const int typ_ = nt_ / 12;            /* 0=q 1=k 2=v (wave-uniform) */    \
      if (typ_ < 2) {                                                           \
        float4 qb4 = *(const float4*)(qkv_b + nt_ * 16 + lg * 4);               \
        const int cc_ = (nt_ - typ_ * 12) * 16 + lg * 4;                        \
        const int h_ = cc_ >> 5, dd_ = cc_ & 31;                                \
        bf16_t* dst_ = &shead[h_][typ_ * 2560 + dd_];                           \
        f32x4 a0 = fzero, a1 = fzero;                                           \
        _Pragma("unroll")                                                       \
        for (int kk = 0; kk < 6; ++kk) {                                        \
          a0 = __builtin_amdgcn_mfma_f32_16x16x32_bf16((WF)[kk], xb0[kk], a0, 0, 0, 0); \
          a1 = __builtin_amdgcn_mfma_f32_16x16x32_bf16((WF)[kk], xb1[kk], a1, 0, 0, 0); \
        }                                                                       \
        bf16x4 p0_ = { tobf(a0[0] + qb4.x), tobf(a0[1] + qb4.y),                \
                       tobf(a0[2] + qb4.z), tobf(a0[3] + qb4.w) };              \
        bf16x4 p1_ = { tobf(a1[0] + qb4.x), tobf(a1[1] + qb4.y),                \
                       tobf(a1[2] + qb4.z), tobf(a1[3] + qb4.w) };              \
        *(bf16x4*)&dst_[((half * 2 + 0) * 16 + li) * 40] = p0_;                 \
        *(bf16x4*)&dst_[((half * 2 + 1) * 16 + li) * 40] = p1_;                 \
      } else {                                                                  \
        const float vb_ = qkv_b[nt_ * 16 + li];                                 \
        const int cc_ = (nt_ - 24) * 16 + li;                                   \
        const int h_ = cc_ >> 5, dd_ = cc_ & 31;                                \
        bf16_t* dst_ = &svt[h_][dd_ * 72];                                      \
        f32x4 a0 = fzero, a1 = fzero;                                           \
        _Pragma("unroll")                                                       \
        for (int kk = 0; kk < 6; ++kk) {                                        \
          a0 = __builtin_amdgcn_mfma_f32_16x16x32_bf16(xb0[kk], (WF)[kk], a0, 0, 0, 0); \
          a1 = __builtin_amdgcn_mfma_f32_16x16x32_bf16(xb1[kk], (WF)[kk], a1, 0, 0, 0); \
        }                                                                       \
        bf16x4 p0_ = { tobf(a0[0] + vb_), tobf(a0[1] + vb_),                    \
                       tobf(a0[2] + vb_), tobf(a0[3] + vb_) };                  \
        bf16x4 p1_ = { tobf(a1[0] + vb_), tobf(a1[1] + vb_),                    \
                       tobf(a1[2] + vb_), tobf(a1[3] + vb_) };                  \
        *(bf16x4*)&dst_[(half * 2 + 0) * 16 + lg * 4] = p0_;                    \
        *(bf16x4*)&dst_[(half * 2 + 1) * 16 + lg * 4] = p1_;                    \
      }                                                                         \
    }

// One half of GEMM1: load x fragments once (12 b128), stream ALL weight tiles
// from L2 (no persistent weight regs -> fits the allocator's 128-reg target).
// Trades LDS-pipe cycles (the contended resource, ~67% busy) for VMEM/L2
// cycles (idle pipe).
#define G1_HALF(H)                                                              \
  {                                                                             \
    const int half = (H);                                                       \
    bf16x8 xb0[6], xb1[6];                                                      \
    _Pragma("unroll")                                                           \
    for (int kk = 0; kk < 6; ++kk) {                                            \
      xb0[kk] = *(const bf16x8*)&sx[((half * 2 + 0) * 16 + li) * 200 + kk * 32 + lg * 8]; \
      xb1[kk] = *(const bf16x8*)&sx[((half * 2 + 1) * 16 + li) * 200 + kk * 32 + lg * 8]; \
    }                                                                           \
    _Pragma("unroll")                                                           \
    for (int j = 0; j < 5; ++j) {                                               \
      if (j < jmax) {                                                           \
        const int nt = wave + 8 * j;                                            \
        bf16x8 wf[6];                                                           \
        const bf16_t* wrow = qkv_wb + (size_t)(nt * 16 + li) * 192 + lg * 8;    \
        _Pragma("unroll")                                                       \
        for (int kk = 0; kk < 6; ++kk) wf[kk] = *(const bf16x8*)(wrow + kk * 32); \
        G1_TILE(nt, wf);                                                        \
      }                                                                         \
    }                                                                           \
  }

// Persistent fused kernel: grid 256 (1/CU), 512 threads (8 waves), 32 windows/block.
// R9 structure (474us: in-register P transpose, sector-paired GEMM2) with the
// LDS-pipe fix done WITHIN the 128-reg budget (the R10 lesson):
//  - GEMM1 half-pass (x reads 108 -> 24 b128/wave/iter) paid for by deleting
//    ALL persistent weight hoists (wf_h, wp_h: 96 regs freed; weights L2-hot)
//  - pf prefetch issued BETWEEN halves: HBM latency hides under half-1 work,
//    not under barrier A's vmcnt(0) drain
//  - mask loads software-pipelined per attn unit (32 regs vs 48-reg burst)
__global__ __launch_bounds__(512, 2) void winattn_fused(
    const float* __restrict__ x,        // [8192,64,192]
    const float* __restrict__ mask,     // [4096,64,64]
    const float* __restrict__ qkv_b,    // [576]
    const float* __restrict__ proj_b,   // [192]
    const bf16_t* __restrict__ qkv_wb,  // [576,192] bf16
    const bf16_t* __restrict__ proj_wb, // [192,192] bf16
    float* __restrict__ out)            // [8192,64,192]
{
  // LDS: 140288 B (1 block/CU)
  __shared__ __align__(16) bf16_t sbuf[2][64 * 200];     // x staging / attn-out (51200 B)
  __shared__ __align__(16) bf16_t shead[6][2 * 64 * 40]; // per head: q[64][40], k[64][40] (61440 B)
  __shared__ __align__(16) bf16_t svt[6][32 * 72];       // per head vT [32][72] (27648 B)

  const int tid  = threadIdx.x;
  const int wave = tid >> 6;
  const int lane = tid & 63;
  const int li   = lane & 15;
  const int lg   = lane >> 4;
  const bool hi  = (lane >= 32);
  const int addr0 = ((((lane >> 4) & 1) << 5) + li) << 2;  // bperm src lane*4, jhi=0
  const int addr1 = addr0 + 64;                            // jhi=1
  const f32x4 fzero = {0.f, 0.f, 0.f, 0.f};

  const int jmax = (wave < 4) ? 5 : 4;     // GEMM1 tiles: nt = wave + 8j < 36
  // G2 sector-pair mapping: waves 0-3: pair=wave, rows 0-63; waves 4,5: pair 4,
  // rows (wave-4&1)*32..; waves 6,7: pair 5.
  const int g2p  = (wave < 4) ? wave : (4 + ((wave - 4) >> 1));
  const int mt0  = (wave < 4) ? 0 : ((wave & 1) ? 2 : 0);
  const int nmt  = (wave < 4) ? 4 : 2;

  // x-staging address map
  int srow[6], scol[6];
#pragma unroll
  for (int j = 0; j < 6; ++j) {
    int id = tid + 512 * j;
    srow[j] = id / 48;
    scol[j] = (id % 48) * 4;
  }

  // ---- prologue: stage window blockIdx.x into sbuf[0] ----
  {
    const float4* src = (const float4*)(x + (size_t)blockIdx.x * 12288);
    float4 p0[6];
#pragma unroll
    for (int j = 0; j < 6; ++j) p0[j] = src[tid + 512 * j];
#pragma unroll
    for (int j = 0; j < 6; ++j) {
      bf16x4 p = { tobf(p0[j].x), tobf(p0[j].y), tobf(p0[j].z), tobf(p0[j].w) };
      *(bf16x4*)&sbuf[0][srow[j] * 200 + scol[j]] = p;
    }
  }
  __syncthreads();

  for (int it = 0; it < 32; ++it) {
    const int b   = blockIdx.x + 256 * (it >> 1) + 4096 * (it & 1);  // mask-paired
    const int cur = it & 1;
    bf16_t* sx = sbuf[cur];
    const bool hasNext = (it < 31);

    // ---- GEMM1 half 0 ----
    G1_HALF(0)

    // issue next-x prefetch between halves: ~900cy HBM latency hides under
    // half-1's loads+MFMAs, so barrier A's vmcnt(0) drain finds it complete.
    float4 pf[6];
    if (hasNext) {
      const int bn = blockIdx.x + 256 * ((it + 1) >> 1) + 4096 * ((it + 1) & 1);
      const float4* src = (const float4*)(x + (size_t)bn * 12288);
#pragma unroll
      for (int j = 0; j < 6; ++j) pf[j] = src[tid + 512 * j];
    }

    // ---- GEMM1 half 1 ----
    G1_HALF(1)

    __syncthreads();   // barrier A: qkv ready

    // ---- attention: 24 units, 3 per wave; mask software-pipelined ----
    const float* maskw = mask + (size_t)(b & 4095) * 4096;
    float4 mcur[4];
    {
      const int ntu = (wave * 3 + 0) & 3;
      const float* mrow = maskw + (ntu * 16 + li) * 64 + lg * 4;
#pragma unroll
      for (int mt = 0; mt < 4; ++mt) mcur[mt] = *(const float4*)(mrow + mt * 16);
    }
#pragma unroll
    for (int uu = 0; uu < 3; ++uu) {
      float4 mnext[4];
      if (uu < 2) {   // issue next unit's mask load early (hides under MFMAs)
        const int ntu = (wave * 3 + uu + 1) & 3;
        const float* mrow = maskw + (ntu * 16 + li) * 64 + lg * 4;
#pragma unroll
        for (int mt = 0; mt < 4; ++mt) mnext[mt] = *(const float4*)(mrow + mt * 16);
      }
      const int unit = wave * 3 + uu;
      const int h  = unit >> 2;
      const int nt = unit & 3;
      const bf16_t* sq = &shead[h][0];
      const bf16_t* sk = &shead[h][2560];
      bf16x8 qf = *(const bf16x8*)&sq[(nt * 16 + li) * 40 + lg * 8];
      f32x4 sacc[4];
#pragma unroll
      for (int mt = 0; mt < 4; ++mt) {
        bf16x8 kf = *(const bf16x8*)&sk[(mt * 16 + li) * 40 + lg * 8];
        sacc[mt] = __builtin_amdgcn_mfma_f32_16x16x32_bf16(kf, qf, fzero, 0, 0, 0);
      }
      float vals[16];
      float rmax = -3.0e38f;
#pragma unroll
      for (int mt = 0; mt < 4; ++mt)
#pragma unroll
        for (int r = 0; r < 4; ++r) {
          float v = sacc[mt][r] * SCALE + ((const float*)&mcur[mt])[r];
          vals[mt * 4 + r] = v;
          rmax = fmaxf(rmax, v);
        }
      rmax = fmaxf(rmax, __shfl_xor(rmax, 16));
      rmax = fmaxf(rmax, __shfl_xor(rmax, 32));
      float rsum = 0.f;
#pragma unroll
      for (int e = 0; e < 16; ++e) {
        float t = __expf(vals[e] - rmax);
        vals[e] = t;
        rsum += t;
      }
      rsum += __shfl_xor(rsum, 16);
      rsum += __shfl_xor(rsum, 32);
      const float inv = __builtin_amdgcn_rcpf(rsum);
      // pack P rows to bf16 pairs (k ascending within u32)
      unsigned int pk[4][2];
#pragma unroll
      for (int mt = 0; mt < 4; ++mt)
#pragma unroll
        for (int h2 = 0; h2 < 2; ++h2) {
          unsigned short ua = bfbits(tobf(vals[mt * 4 + 2 * h2] * inv));
          unsigned short ub = bfbits(tobf(vals[mt * 4 + 2 * h2 + 1] * inv));
          pk[mt][h2] = (unsigned int)ua | ((unsigned int)ub << 16);
        }
      // in-register transpose (R8/R9-verified): B-operand lane (li,lg) needs
      // P[q=li][k=32ks+8lg+e]; fixed 4-group lane exchange via ds_bpermute.
      f32x4 o0 = fzero, o1 = fzero;
#pragma unroll
      for (int ks = 0; ks < 2; ++ks) {
        int e0 = __builtin_amdgcn_ds_bpermute(addr0, (int)pk[2 * ks][0]);
        int e1 = __builtin_amdgcn_ds_bpermute(addr0, (int)pk[2 * ks][1]);
        int e2 = __builtin_amdgcn_ds_bpermute(addr1, (int)pk[2 * ks][0]);
        int e3 = __builtin_amdgcn_ds_bpermute(addr1, (int)pk[2 * ks][1]);
        int f0 = __builtin_amdgcn_ds_bpermute(addr0, (int)pk[2 * ks + 1][0]);
        int f1 = __builtin_amdgcn_ds_bpermute(addr0, (int)pk[2 * ks + 1][1]);
        int f2 = __builtin_amdgcn_ds_bpermute(addr1, (int)pk[2 * ks + 1][0]);
        int f3 = __builtin_amdgcn_ds_bpermute(addr1, (int)pk[2 * ks + 1][1]);
        union { int u[4]; bf16x8 v; } cv;
        cv.u[0] = hi ? f0 : e0;
        cv.u[1] = hi ? f1 : e1;
        cv.u[2] = hi ? f2 : e2;
        cv.u[3] = hi ? f3 : e3;
        bf16x8 pfr = cv.v;
        bf16x8 v0  = *(const bf16x8*)&svt[h][li * 72 + ks * 32 + lg * 8];
        bf16x8 v1  = *(const bf16x8*)&svt[h][(16 + li) * 72 + ks * 32 + lg * 8];
        o0 = __builtin_amdgcn_mfma_f32_16x16x32_bf16(v0, pfr, o0, 0, 0, 0);
        o1 = __builtin_amdgcn_mfma_f32_16x16x32_bf16(v1, pfr, o1, 0, 0, 0);
      }
      bf16x4 p0 = { tobf(o0[0]), tobf(o0[1]), tobf(o0[2]), tobf(o0[3]) };
      bf16x4 p1 = { tobf(o1[0]), tobf(o1[1]), tobf(o1[2]), tobf(o1[3]) };
      bf16_t* so = &sx[(nt * 16 + li) * 200 + h * 32 + lg * 4];
      *(bf16x4*)&so[0]  = p0;
      *(bf16x4*)&so[16] = p1;
      if (uu < 2) {
#pragma unroll
        for (int mt = 0; mt < 4; ++mt) mcur[mt] = mnext[mt];
      }
    }

    // write prefetched next-window x into the other buffer
    if (hasNext) {
      bf16_t* nx = sbuf[cur ^ 1];
#pragma unroll
      for (int j = 0; j < 6; ++j) {
        bf16x4 p = { tobf(pf[j].x), tobf(pf[j].y), tobf(pf[j].z), tobf(pf[j].w) };
        *(bf16x4*)&nx[srow[j] * 200 + scol[j]] = p;
      }
    }
    __syncthreads();   // barrier B: attn-out + next-x staged

    // ---- GEMM2: out = so @ proj_w^T + proj_b (sector-paired) ----
    // proj tiles streamed from L2 at phase start (73KB, L2-hot; live only
    // through G2). Every wave writes both 64B halves of its 128B sectors.
    {
      float* ob = out + (size_t)b * 12288;
      bf16x8 wp0[6], wp1[6];
      {
        const bf16_t* wr0 = proj_wb + (size_t)((2 * g2p + 0) * 16 + li) * 192 + lg * 8;
        const bf16_t* wr1 = proj_wb + (size_t)((2 * g2p + 1) * 16 + li) * 192 + lg * 8;
#pragma unroll
        for (int kk = 0; kk < 6; ++kk) {
          wp0[kk] = *(const bf16x8*)(wr0 + kk * 32);
          wp1[kk] = *(const bf16x8*)(wr1 + kk * 32);
        }
      }
      const float4 pb0 = *(const float4*)(proj_b + (2 * g2p + 0) * 16 + lg * 4);
      const float4 pb1 = *(const float4*)(proj_b + (2 * g2p + 1) * 16 + lg * 4);
      for (int m = 0; m < nmt; ++m) {
        const int mt = mt0 + m;
        bf16x8 sb[6];
#pragma unroll
        for (int kk = 0; kk < 6; ++kk)
          sb[kk] = *(const bf16x8*)&sx[(mt * 16 + li) * 200 + kk * 32 + lg * 8];
        f32x4 a0 = fzero, a1 = fzero;
#pragma unroll
        for (int kk = 0; kk < 6; ++kk) {
          a0 = __builtin_amdgcn_mfma_f32_16x16x32_bf16(wp0[kk], sb[kk], a0, 0, 0, 0);
          a1 = __builtin_amdgcn_mfma_f32_16x16x32_bf16(wp1[kk], sb[kk], a1, 0, 0, 0);
        }
        float4 o0 = { a0[0] + pb0.x, a0[1] + pb0.y, a0[2] + pb0.z, a0[3] + pb0.w };
        float4 o1 = { a1[0] + pb1.x, a1[1] + pb1.y, a1[2] + pb1.z, a1[3] + pb1.w };
        float* orow = ob + (size_t)(mt * 16 + li) * 192 + (2 * g2p) * 16 + lg * 4;
        *(float4*)(orow)      = o0;
        *(float4*)(orow + 16) = o1;
      }
    }
    // no barrier: next window's GEMM1 touches shead/svt only and reads
    // sbuf[cur^1]; the next prefetch-write to sbuf[cur] is ordered by barrier A.
  }
}

extern "C" void kernel_launch(void* const* d_in, const int* in_sizes, int n_in,
                              void* d_out, int out_size, void* d_ws, size_t ws_size,
                              hipStream_t stream) {
  const float* x      = (const float*)d_in[0];
  const float* mask   = (const float*)d_in[1];
  const float* qkv_w  = (const float*)d_in[2];
  const float* qkv_b  = (const float*)d_in[3];
  const float* proj_w = (const float*)d_in[4];
  const float* proj_b = (const float*)d_in[5];
  float* out = (float*)d_out;

  bf16_t* qkv_wb  = (bf16_t*)d_ws;
  bf16_t* proj_wb = qkv_wb + 576 * 192;

  cvt_weights<<<432, 256, 0, stream>>>(qkv_w, proj_w, qkv_wb, proj_wb);
  winattn_fused<<<256, 512, 0, stream>>>(x, mask, qkv_b, proj_b, qkv_wb, proj_wb, out);
}

// Round 12
// 466.269 us; speedup vs baseline: 1.6259x; 1.6259x over previous
//
#include <hip/hip_runtime.h>
#include <hip/hip_bf16.h>
#include <stdint.h>

typedef __bf16 bf16_t;
typedef __bf16 bf16x4 __attribute__((ext_vector_type(4)));
typedef __bf16 bf16x8 __attribute__((ext_vector_type(8)));
typedef float  f32x4  __attribute__((ext_vector_type(4)));

#define SCALE 0.17677669529663687f   // (192/6)^-0.5

__device__ __forceinline__ bf16_t tobf(float f) { return (bf16_t)f; }
__device__ __forceinline__ unsigned short bfbits(bf16_t v) {
  union { bf16_t f; unsigned short s; } u; u.f = v; return u.s;
}

__global__ void cvt_weights(const float* __restrict__ qkv_w,
                            const float* __restrict__ proj_w,
                            bf16_t* __restrict__ qkv_wb,
                            bf16_t* __restrict__ proj_wb)
{
  int i = blockIdx.x * 256 + threadIdx.x;
  if (i < 576 * 192) qkv_wb[i] = tobf(qkv_w[i]);
  if (i < 192 * 192) proj_wb[i] = tobf(proj_w[i]);
}

// Persistent fused kernel: grid 256 (1/CU), 512 threads (8 waves), 32 windows/block.
// EXACT R9 structure (474us: in-register P transpose via ds_bpermute,
// sector-paired GEMM2, per-tile GEMM1 — do NOT touch GEMM1, R10/R11 proved any
// multi-tile x-fragment hold spills) + attn serial-chain shortening only:
//  (1) tree reductions for rmax/rsum (depth 4, not 16 sequential)
//  (2) DEFERRED normalization: P packed unnormalized (exp in (0,1]);
//      the x(1/sum) applied to the 8 f32 PV outputs. The pack->bpermute->MFMA
//      chain now depends only on exp, not on rsum/shfl/rcp/muls.
__global__ __launch_bounds__(512, 2) void winattn_fused(
    const float* __restrict__ x,        // [8192,64,192]
    const float* __restrict__ mask,     // [4096,64,64]
    const float* __restrict__ qkv_b,    // [576]
    const float* __restrict__ proj_b,   // [192]
    const bf16_t* __restrict__ qkv_wb,  // [576,192] bf16
    const bf16_t* __restrict__ proj_wb, // [192,192] bf16
    float* __restrict__ out)            // [8192,64,192]
{
  // LDS: 140288 B (1 block/CU)
  __shared__ __align__(16) bf16_t sbuf[2][64 * 200];     // x staging / attn-out (51200 B)
  __shared__ __align__(16) bf16_t shead[6][2 * 64 * 40]; // per head: q[64][40], k[64][40] (61440 B)
  __shared__ __align__(16) bf16_t svt[6][32 * 72];       // per head vT [32][72] (27648 B)

  const int tid  = threadIdx.x;
  const int wave = tid >> 6;
  const int lane = tid & 63;
  const int li   = lane & 15;
  const int lg   = lane >> 4;
  const bool hi  = (lane >= 32);
  const int addr0 = ((((lane >> 4) & 1) << 5) + li) << 2;  // bperm src lane*4, jhi=0
  const int addr1 = addr0 + 64;                            // jhi=1
  const f32x4 fzero = {0.f, 0.f, 0.f, 0.f};

  // ---- hoist weights (constant across windows) ----
  const int jmax = (wave < 4) ? 5 : 4;     // GEMM1 tiles: nt = wave + 8j < 36
  bf16x8 wf_h[2][6];                       // first 2 GEMM1 tiles (48 VGPR)
#pragma unroll
  for (int j = 0; j < 2; ++j) {
    const int nt = wave + 8 * j;
    const bf16_t* wrow = qkv_wb + (size_t)(nt * 16 + li) * 192 + lg * 8;
#pragma unroll
    for (int kk = 0; kk < 6; ++kk) wf_h[j][kk] = *(const bf16x8*)(wrow + kk * 32);
  }
  // G2 sector-pair mapping: waves 0-3: pair=wave, rows 0-63; waves 4,5: pair 4,
  // rows (wave-4)*32..; waves 6,7: pair 5. Every wave hoists its ct pair.
  const int g2p  = (wave < 4) ? wave : (4 + ((wave - 4) >> 1));
  const int mt0  = (wave < 4) ? 0 : ((wave & 1) ? 2 : 0);
  const int nmt  = (wave < 4) ? 4 : 2;
  bf16x8 wp_h[2][6];                       // proj tiles (48 VGPR)
#pragma unroll
  for (int c = 0; c < 2; ++c) {
    const int ct = 2 * g2p + c;
    const bf16_t* wrow = proj_wb + (size_t)(ct * 16 + li) * 192 + lg * 8;
#pragma unroll
    for (int kk = 0; kk < 6; ++kk) wp_h[c][kk] = *(const bf16x8*)(wrow + kk * 32);
  }

  // x-staging address map
  int srow[6], scol[6];
#pragma unroll
  for (int j = 0; j < 6; ++j) {
    int id = tid + 512 * j;
    srow[j] = id / 48;
    scol[j] = (id % 48) * 4;
  }
  float4 pf[6];

  // ---- prologue: stage window blockIdx.x into sbuf[0] ----
  {
    const float4* src = (const float4*)(x + (size_t)blockIdx.x * 12288);
#pragma unroll
    for (int j = 0; j < 6; ++j) pf[j] = src[tid + 512 * j];
#pragma unroll
    for (int j = 0; j < 6; ++j) {
      bf16x4 p = { tobf(pf[j].x), tobf(pf[j].y), tobf(pf[j].z), tobf(pf[j].w) };
      *(bf16x4*)&sbuf[0][srow[j] * 200 + scol[j]] = p;
    }
  }
  __syncthreads();

  for (int it = 0; it < 32; ++it) {
    const int b   = blockIdx.x + 256 * (it >> 1) + 4096 * (it & 1);  // mask-paired
    const int cur = it & 1;
    bf16_t* sx = sbuf[cur];

    const bool hasNext = (it < 31);
    if (hasNext) {   // prefetch next window's x (regs held through attn phase)
      const int bn = blockIdx.x + 256 * ((it + 1) >> 1) + 4096 * ((it + 1) & 1);
      const float4* src = (const float4*)(x + (size_t)bn * 12288);
#pragma unroll
      for (int j = 0; j < 6; ++j) pf[j] = src[tid + 512 * j];
    }

    // ---- GEMM1: qkv = x @ qkv_w^T + b (R9 per-tile form — don't touch) ----
    for (int j = 0; j < jmax; ++j) {
      const int nt = wave + 8 * j;
      const int typ = nt / 12;             // 0=q 1=k 2=v
      bf16x8 wf[6];
      if (j < 2) {
#pragma unroll
        for (int kk = 0; kk < 6; ++kk) wf[kk] = wf_h[j][kk];
      } else {
        const bf16_t* wrow = qkv_wb + (size_t)(nt * 16 + li) * 192 + lg * 8;
#pragma unroll
        for (int kk = 0; kk < 6; ++kk) wf[kk] = *(const bf16x8*)(wrow + kk * 32);
      }
      if (typ < 2) {
        // swapped: D[wcol][token]; lane -> 4 consecutive d of one token
        float4 qb4 = *(const float4*)(qkv_b + nt * 16 + lg * 4);
        const int cc = (nt - typ * 12) * 16 + lg * 4;
        const int h = cc >> 5, dd = cc & 31;
        bf16_t* dst = &shead[h][typ * 2560 + dd];
#pragma unroll
        for (int mt = 0; mt < 4; ++mt) {
          f32x4 a = fzero;
#pragma unroll
          for (int kk = 0; kk < 6; ++kk) {
            bf16x8 xb = *(const bf16x8*)&sx[(mt * 16 + li) * 200 + kk * 32 + lg * 8];
            a = __builtin_amdgcn_mfma_f32_16x16x32_bf16(wf[kk], xb, a, 0, 0, 0);
          }
          bf16x4 pk = { tobf(a[0] + qb4.x), tobf(a[1] + qb4.y),
                        tobf(a[2] + qb4.z), tobf(a[3] + qb4.w) };
          *(bf16x4*)&dst[(mt * 16 + li) * 40] = pk;
        }
      } else {
        // direct: D[token][wcol]; store vT[d][tok] bf16x4 along tok
        const float vb = qkv_b[nt * 16 + li];
        const int cc = (nt - 24) * 16 + li;
        const int h = cc >> 5, dd = cc & 31;
        bf16_t* dst = &svt[h][dd * 72];
#pragma unroll
        for (int mt = 0; mt < 4; ++mt) {
          f32x4 a = fzero;
#pragma unroll
          for (int kk = 0; kk < 6; ++kk) {
            bf16x8 xb = *(const bf16x8*)&sx[(mt * 16 + li) * 200 + kk * 32 + lg * 8];
            a = __builtin_amdgcn_mfma_f32_16x16x32_bf16(xb, wf[kk], a, 0, 0, 0);
          }
          bf16x4 pk = { tobf(a[0] + vb), tobf(a[1] + vb),
                        tobf(a[2] + vb), tobf(a[3] + vb) };
          *(bf16x4*)&dst[mt * 16 + lg * 4] = pk;
        }
      }
    }
    __syncthreads();   // barrier A: qkv ready

    // ---- mask burst: all 3 units' rows, one latency ----
    float4 mreg[3][4];
    {
      const float* maskw = mask + (size_t)(b & 4095) * 4096;
#pragma unroll
      for (int uu = 0; uu < 3; ++uu) {
        const int ntu = (wave * 3 + uu) & 3;
        const float* mrow = maskw + (ntu * 16 + li) * 64 + lg * 4;
#pragma unroll
        for (int mt = 0; mt < 4; ++mt) mreg[uu][mt] = *(const float4*)(mrow + mt * 16);
      }
    }

    // ---- attention: 24 units, 3 per wave; P transposed IN-REGISTER ----
#pragma unroll
    for (int uu = 0; uu < 3; ++uu) {
      const int unit = wave * 3 + uu;
      const int h  = unit >> 2;
      const int nt = unit & 3;
      const bf16_t* sq = &shead[h][0];
      const bf16_t* sk = &shead[h][2560];
      bf16x8 qf = *(const bf16x8*)&sq[(nt * 16 + li) * 40 + lg * 8];
      f32x4 sacc[4];
#pragma unroll
      for (int mt = 0; mt < 4; ++mt) {
        bf16x8 kf = *(const bf16x8*)&sk[(mt * 16 + li) * 40 + lg * 8];
        sacc[mt] = __builtin_amdgcn_mfma_f32_16x16x32_bf16(kf, qf, fzero, 0, 0, 0);
      }
      float vals[16];
#pragma unroll
      for (int mt = 0; mt < 4; ++mt)
#pragma unroll
        for (int r = 0; r < 4; ++r)
          vals[mt * 4 + r] = sacc[mt][r] * SCALE + ((const float*)&mreg[uu][mt])[r];
      // tree max (depth 4, v_max3-friendly) instead of 16 sequential fmax
      float m0 = fmaxf(fmaxf(vals[0],  vals[1]),  fmaxf(vals[2],  vals[3]));
      float m1 = fmaxf(fmaxf(vals[4],  vals[5]),  fmaxf(vals[6],  vals[7]));
      float m2 = fmaxf(fmaxf(vals[8],  vals[9]),  fmaxf(vals[10], vals[11]));
      float m3 = fmaxf(fmaxf(vals[12], vals[13]), fmaxf(vals[14], vals[15]));
      float rmax = fmaxf(fmaxf(m0, m1), fmaxf(m2, m3));
      rmax = fmaxf(rmax, __shfl_xor(rmax, 16));
      rmax = fmaxf(rmax, __shfl_xor(rmax, 32));
#pragma unroll
      for (int e = 0; e < 16; ++e) vals[e] = __expf(vals[e] - rmax);
      // tree sum; NORMALIZATION DEFERRED to the f32 PV outputs, so the
      // pack+bpermute+MFMA below depend only on exp, not on rsum/rcp.
      float s0 = (vals[0]  + vals[1])  + (vals[2]  + vals[3]);
      float s1 = (vals[4]  + vals[5])  + (vals[6]  + vals[7]);
      float s2 = (vals[8]  + vals[9])  + (vals[10] + vals[11]);
      float s3 = (vals[12] + vals[13]) + (vals[14] + vals[15]);
      float rsum = (s0 + s1) + (s2 + s3);
      rsum += __shfl_xor(rsum, 16);
      rsum += __shfl_xor(rsum, 32);
      const float inv = __builtin_amdgcn_rcpf(rsum);
      // pack UNNORMALIZED P rows (exp in (0,1], full bf16 relative precision)
      unsigned int pk[4][2];
#pragma unroll
      for (int mt = 0; mt < 4; ++mt)
#pragma unroll
        for (int h2 = 0; h2 < 2; ++h2) {
          unsigned short ua = bfbits(tobf(vals[mt * 4 + 2 * h2]));
          unsigned short ub = bfbits(tobf(vals[mt * 4 + 2 * h2 + 1]));
          pk[mt][h2] = (unsigned int)ua | ((unsigned int)ub << 16);
        }
      // in-register transpose (R8/R9-verified): B-operand lane (li,lg) needs
      // P[q=li][k=32ks+8lg+e]; fixed 4-group lane exchange via ds_bpermute.
      f32x4 o0 = fzero, o1 = fzero;
#pragma unroll
      for (int ks = 0; ks < 2; ++ks) {
        int e0 = __builtin_amdgcn_ds_bpermute(addr0, (int)pk[2 * ks][0]);
        int e1 = __builtin_amdgcn_ds_bpermute(addr0, (int)pk[2 * ks][1]);
        int e2 = __builtin_amdgcn_ds_bpermute(addr1, (int)pk[2 * ks][0]);
        int e3 = __builtin_amdgcn_ds_bpermute(addr1, (int)pk[2 * ks][1]);
        int f0 = __builtin_amdgcn_ds_bpermute(addr0, (int)pk[2 * ks + 1][0]);
        int f1 = __builtin_amdgcn_ds_bpermute(addr0, (int)pk[2 * ks + 1][1]);
        int f2 = __builtin_amdgcn_ds_bpermute(addr1, (int)pk[2 * ks + 1][0]);
        int f3 = __builtin_amdgcn_ds_bpermute(addr1, (int)pk[2 * ks + 1][1]);
        union { int u[4]; bf16x8 v; } cv;
        cv.u[0] = hi ? f0 : e0;
        cv.u[1] = hi ? f1 : e1;
        cv.u[2] = hi ? f2 : e2;
        cv.u[3] = hi ? f3 : e3;
        bf16x8 pfr = cv.v;
        bf16x8 v0  = *(const bf16x8*)&svt[h][li * 72 + ks * 32 + lg * 8];
        bf16x8 v1  = *(const bf16x8*)&svt[h][(16 + li) * 72 + ks * 32 + lg * 8];
        o0 = __builtin_amdgcn_mfma_f32_16x16x32_bf16(v0, pfr, o0, 0, 0, 0);
        o1 = __builtin_amdgcn_mfma_f32_16x16x32_bf16(v1, pfr, o1, 0, 0, 0);
      }
      // apply deferred 1/sum here (8 f32 muls on the PV outputs)
      bf16x4 p0 = { tobf(o0[0] * inv), tobf(o0[1] * inv),
                    tobf(o0[2] * inv), tobf(o0[3] * inv) };
      bf16x4 p1 = { tobf(o1[0] * inv), tobf(o1[1] * inv),
                    tobf(o1[2] * inv), tobf(o1[3] * inv) };
      bf16_t* so = &sx[(nt * 16 + li) * 200 + h * 32 + lg * 4];
      *(bf16x4*)&so[0]  = p0;
      *(bf16x4*)&so[16] = p1;
    }

    // write prefetched next-window x into the other buffer
    if (hasNext) {
      bf16_t* nx = sbuf[cur ^ 1];
#pragma unroll
      for (int j = 0; j < 6; ++j) {
        bf16x4 p = { tobf(pf[j].x), tobf(pf[j].y), tobf(pf[j].z), tobf(pf[j].w) };
        *(bf16x4*)&nx[srow[j] * 200 + scol[j]] = p;
      }
    }
    __syncthreads();   // barrier B: attn-out + next-x staged

    // ---- GEMM2: out = so @ proj_w^T + proj_b (sector-paired, weights in regs) ----
    // Every wave computes BOTH ct tiles of its 128B sector pair and stores the
    // two 64B halves back-to-back -> full-line writes from a single wave.
    {
      float* ob = out + (size_t)b * 12288;
      const float4 pb0 = *(const float4*)(proj_b + (2 * g2p + 0) * 16 + lg * 4);
      const float4 pb1 = *(const float4*)(proj_b + (2 * g2p + 1) * 16 + lg * 4);
      for (int m = 0; m < nmt; ++m) {
        const int mt = mt0 + m;
        bf16x8 sb[6];
#pragma unroll
        for (int kk = 0; kk < 6; ++kk)
          sb[kk] = *(const bf16x8*)&sx[(mt * 16 + li) * 200 + kk * 32 + lg * 8];
        f32x4 a0 = fzero, a1 = fzero;
#pragma unroll
        for (int kk = 0; kk < 6; ++kk) {
          a0 = __builtin_amdgcn_mfma_f32_16x16x32_bf16(wp_h[0][kk], sb[kk], a0, 0, 0, 0);
          a1 = __builtin_amdgcn_mfma_f32_16x16x32_bf16(wp_h[1][kk], sb[kk], a1, 0, 0, 0);
        }
        float4 o0 = { a0[0] + pb0.x, a0[1] + pb0.y, a0[2] + pb0.z, a0[3] + pb0.w };
        float4 o1 = { a1[0] + pb1.x, a1[1] + pb1.y, a1[2] + pb1.z, a1[3] + pb1.w };
        float* orow = ob + (size_t)(mt * 16 + li) * 192 + (2 * g2p) * 16 + lg * 4;
        *(float4*)(orow)      = o0;
        *(float4*)(orow + 16) = o1;
      }
    }
    // no barrier: next window's GEMM1 touches shead/svt only and reads
    // sbuf[cur^1]; the next prefetch-write to sbuf[cur] is ordered by barrier A.
  }
}

extern "C" void kernel_launch(void* const* d_in, const int* in_sizes, int n_in,
                              void* d_out, int out_size, void* d_ws, size_t ws_size,
                              hipStream_t stream) {
  const float* x      = (const float*)d_in[0];
  const float* mask   = (const float*)d_in[1];
  const float* qkv_w  = (const float*)d_in[2];
  const float* qkv_b  = (const float*)d_in[3];
  const float* proj_w = (const float*)d_in[4];
  const float* proj_b = (const float*)d_in[5];
  float* out = (float*)d_out;

  bf16_t* qkv_wb  = (bf16_t*)d_ws;
  bf16_t* proj_wb = qkv_wb + 576 * 192;

  cvt_weights<<<432, 256, 0, stream>>>(qkv_w, proj_w, qkv_wb, proj_wb);
  winattn_fused<<<256, 512, 0, stream>>>(x, mask, qkv_b, proj_b, qkv_wb, proj_wb, out);
}